// Round 11
// baseline (475.138 us; speedup 1.0000x reference)
//
#include <hip/hip_runtime.h>
#include <cstdint>
#include <cstddef>

// ---------------------------------------------------------------------------
// MultiHeadExternalAttention, algebraically collapsed. Round 11 = DIAGNOSTIC:
// real pipeline identical to round 10 (84.8 us, passes); appended repeat-
// probes (write to dead ws scratch) to surface full rocprof counters above
// the 40-us fill dispatches and split gemm cost into stage/compute/epilogue.
//   probe_a<0> full x4   | probe_a<1> stage only on rep0 | probe_a<2> no epi
//   stage/rep=(T0-T1)/3, epi/rep=(T0-T2)/4, warm-compute from T1.
// ---------------------------------------------------------------------------

typedef unsigned short u16;
typedef unsigned int u32;
typedef short s16x8 __attribute__((ext_vector_type(8)));
typedef float f32x4 __attribute__((ext_vector_type(4)));

// workspace layout (bytes)
constexpr size_t OFF_WKT  = 1u << 20;                 // u16 [256][512]
constexpr size_t OFF_WVT  = OFF_WKT + (1u << 18);     // u16 [512][256]
constexpr size_t OFF_BK   = OFF_WVT + (1u << 18);     // f32 [256]
constexpr size_t OFF_BV   = OFF_BK + 4096;            // f32 [512]
constexpr size_t OFF_INV  = OFF_BV + 4096;            // f32 [32][256]
constexpr size_t OFF_CP   = 2u << 20;                 // f32 [256][256]
constexpr size_t OFF_LOG  = 4u << 20;                 // u16 [32768][256] (16 MiB)
constexpr size_t OFF_WVP  = 40u << 20;                // f32 partials (4 MiB)
constexpr size_t OFF_BVP  = 45u << 20;                // f32 partials (256 KiB)
// probe scratch (dead — never validated)
constexpr size_t OFF_PLOG = 64u << 20;                // u16 16 MiB
constexpr size_t OFF_PCP  = 82u << 20;                // f32 small
constexpr size_t OFF_POUT = 96u << 20;                // f32 64 MiB

__device__ __forceinline__ float bf2f(u16 v) {
  union { u32 u; float f; } c; c.u = ((u32)v) << 16; return c.f;
}
__device__ __forceinline__ u16 f2bf(float f) {
  union { float f; u32 u; } c; c.f = f;
  u32 u = c.u;
  u += 0x7fffu + ((u >> 16) & 1u);
  return (u16)(u >> 16);
}
__device__ __forceinline__ u32 cvt2(float lo, float hi) {
  u32 r;
  asm("v_cvt_pk_bf16_f32 %0, %1, %2" : "=v"(r) : "v"(lo), "v"(hi));
  return r;
}
__device__ __forceinline__ uint4 pack_bf8(float4 lo, float4 hi) {
  return make_uint4(cvt2(lo.x, lo.y), cvt2(lo.z, lo.w),
                    cvt2(hi.x, hi.y), cvt2(hi.z, hi.w));
}
__device__ __forceinline__ s16x8 as_s16x8(uint4 v) {
  union { uint4 u; s16x8 s; } c; c.u = v; return c.s;
}
__device__ __forceinline__ void mfma_bf16(f32x4& acc, s16x8 a, s16x8 b) {
  asm volatile("v_mfma_f32_16x16x32_bf16 %0, %1, %2, %0"
               : "+v"(acc) : "v"(a), "v"(b));
}
__device__ __forceinline__ void gl16(const void* g, void* l) {
  __builtin_amdgcn_global_load_lds(
      (const __attribute__((address_space(1))) void*)g,
      (__attribute__((address_space(3))) void*)l, 16, 0, 0);
}

// ---------------------------------------------------------------------------
__global__ void prep_wkt(const float* __restrict__ wi, const float* __restrict__ wm,
                         u16* __restrict__ wkT) {
  const int gid = blockIdx.x * 256 + threadIdx.x;
  const int hm = gid & 255, e = gid >> 8;
  const int h = hm >> 4, m = hm & 15;
  float acc = 0.f;
  for (int d = 0; d < 128; d++)
    acc += wi[e * 2048 + h * 128 + d] * wm[d * 16 + m];
  wkT[hm * 512 + e] = f2bf(acc);
}

__global__ __launch_bounds__(256) void wvt_part(const float* __restrict__ mv,
                                                const float* __restrict__ b_mv,
                                                const float* __restrict__ wo,
                                                float* __restrict__ wvp,
                                                float* __restrict__ bvp) {
  __shared__ float wmv_l[16][16];
  __shared__ float bmv_l[16];
  const int blk = blockIdx.x;
  const int h = blk >> 3, dc = blk & 7;
  const int t = threadIdx.x;
  {
    const int m = t >> 4, dd = t & 15;
    wmv_l[m][dd] = mv[m * 128 + dc * 16 + dd];
    if (t < 16) bmv_l[t] = b_mv[dc * 16 + t];
  }
  __syncthreads();
  float acc0[16], acc1[16];
  float bv0 = 0.f, bv1 = 0.f;
#pragma unroll
  for (int m = 0; m < 16; m++) { acc0[m] = 0.f; acc1[m] = 0.f; }
#pragma unroll
  for (int dd = 0; dd < 16; dd++) {
    const float w0 = wo[(size_t)(h * 128 + dc * 16 + dd) * 512 + t];
    const float w1 = wo[(size_t)(h * 128 + dc * 16 + dd) * 512 + 256 + t];
#pragma unroll
    for (int m = 0; m < 16; m++) {
      const float c = wmv_l[m][dd];
      acc0[m] += c * w0;
      acc1[m] += c * w1;
    }
    bv0 += bmv_l[dd] * w0;
    bv1 += bmv_l[dd] * w1;
  }
  float* w0p = wvp + ((size_t)blk * 512 + t) * 16;
  float* w1p = wvp + ((size_t)blk * 512 + 256 + t) * 16;
#pragma unroll
  for (int m = 0; m < 16; m++) { w0p[m] = acc0[m]; w1p[m] = acc1[m]; }
  bvp[(size_t)blk * 512 + t] = bv0;
  bvp[(size_t)blk * 512 + 256 + t] = bv1;
}

__global__ __launch_bounds__(256) void wvt_fin(const float* __restrict__ wvp,
                                               const float* __restrict__ bvp,
                                               const float* __restrict__ b_out,
                                               u16* __restrict__ wvT,
                                               float* __restrict__ bv) {
  const int e = blockIdx.x;
  const int t = threadIdx.x;
  const int h = t >> 4, m = t & 15;
  float s = 0.f;
#pragma unroll
  for (int dc = 0; dc < 8; dc++)
    s += wvp[((size_t)(h * 8 + dc) * 512 + e) * 16 + m];
  wvT[(size_t)e * 256 + t] = f2bf(s);
  if (t < 64) {
    float b = bvp[(size_t)t * 512 + e] + bvp[(size_t)(t + 64) * 512 + e];
#pragma unroll
    for (int mask = 32; mask >= 1; mask >>= 1) b += __shfl_xor(b, mask);
    if (t == 0) bv[e] = b_out[e] + b;
  }
}

__global__ void prep_bk(const float* __restrict__ b_in, const float* __restrict__ wm,
                        const float* __restrict__ b_mk, float* __restrict__ bk) {
  const int t = threadIdx.x;
  const int h = t >> 4, m = t & 15;
  float acc = b_mk[m];
  for (int d = 0; d < 128; d++) acc += b_in[h * 128 + d] * wm[d * 16 + m];
  bk[t] = acc;
}

// ---------------------------------------------------------------------------
// GEMM A (round-10 structure, unchanged)
__global__ __launch_bounds__(256, 4) void gemm_a(const float* __restrict__ x,
                                                 const u16* __restrict__ wkT,
                                                 const float* __restrict__ bk,
                                                 u16* __restrict__ logits,
                                                 float* __restrict__ cpart) {
  __shared__ float Asf[4096];
  __shared__ u16 Bs[4096];
  __shared__ float cs[2][128];
  const int t = threadIdx.x;
  const int l = t & 63, w = t >> 6;
  const int wr = w >> 1, wc = w & 1;
  const int lrow = l & 15, lkg = l >> 4;
  const int gCol0 = blockIdx.x << 7;
  const int gRow0 = blockIdx.y << 7;

  const char* xb = (const char*)x;
  const char* wb = (const char*)wkT;
  const char* gA[4]; char* lA[4];
  const char* gB[2]; char* lB[2];
#pragma unroll
  for (int p = 0; p < 4; p++) {
    const int o = p * 4096 + t * 16;
    const int row = o >> 7, inner = o & 127;
    const int linner = inner ^ ((row & 7) << 4);
    gA[p] = xb + (size_t)(gRow0 + row) * 2048 + linner;
    lA[p] = (char*)Asf + o;
  }
#pragma unroll
  for (int p = 0; p < 2; p++) {
    const int c = p * 256 + t;
    const int kg = c >> 7, col = c & 127;
    gB[p] = wb + (size_t)(gCol0 + col) * 1024 + kg * 16;
    lB[p] = (char*)Bs + c * 16;
  }

  f32x4 acc[4][4];
#pragma unroll
  for (int i = 0; i < 4; i++)
#pragma unroll
    for (int n = 0; n < 4; n++) acc[i][n] = f32x4{0.f, 0.f, 0.f, 0.f};

  for (int kc = 0; kc < 16; ++kc) {
    __syncthreads();
#pragma unroll
    for (int p = 0; p < 4; p++) gl16(gA[p] + kc * 128, lA[p]);
#pragma unroll
    for (int p = 0; p < 2; p++) gl16(gB[p] + kc * 64, lB[p]);
    __syncthreads();

    s16x8 af[4];
#pragma unroll
    for (int i = 0; i < 4; i++) {
      const int r = wr * 64 + i * 16 + lrow;
      const int iw0 = (lkg << 5) ^ ((r & 7) << 4);
      const float4 a0 = *(const float4*)&Asf[r * 32 + (iw0 >> 2)];
      const float4 a1 = *(const float4*)&Asf[r * 32 + ((iw0 ^ 16) >> 2)];
      af[i] = as_s16x8(pack_bf8(a0, a1));
    }
#pragma unroll
    for (int n = 0; n < 4; n++) {
      const s16x8 bfr =
          *(const s16x8*)&Bs[(lkg * 128 + wc * 64 + n * 16 + lrow) * 8];
#pragma unroll
      for (int i = 0; i < 4; i++) mfma_bf16(acc[i][n], af[i], bfr);
    }
  }

  asm volatile("s_nop 7\n\ts_nop 7");
  const int crow = lkg * 4;
  float esum[4];
#pragma unroll
  for (int n = 0; n < 4; n++) {
    const int col = gCol0 + wc * 64 + n * 16 + lrow;
    const float bias = bk[col];
    float es = 0.f;
#pragma unroll
    for (int i = 0; i < 4; i++) {
      const int row0 = gRow0 + wr * 64 + i * 16 + crow;
#pragma unroll
      for (int j = 0; j < 4; j++) {
        const u16 q = f2bf(acc[i][n][j] + bias);
        logits[(size_t)(row0 + j) * 256 + col] = q;
        es += __expf(bf2f(q));
      }
    }
    esum[n] = es;
  }
#pragma unroll
  for (int n = 0; n < 4; n++) {
    esum[n] += __shfl_xor(esum[n], 16);
    esum[n] += __shfl_xor(esum[n], 32);
  }
  if (l < 16) {
#pragma unroll
    for (int n = 0; n < 4; n++) cs[wr][wc * 64 + n * 16 + l] = esum[n];
  }
  __syncthreads();
  if (t < 128)
    cpart[(size_t)blockIdx.y * 256 + gCol0 + t] = cs[0][t] + cs[1][t];
}

__global__ void colsum_fin(const float* __restrict__ cpart, float* __restrict__ inv) {
  const int b = blockIdx.x, hm = threadIdx.x;
  float s = 0.f;
#pragma unroll
  for (int k = 0; k < 8; k++) s += cpart[(size_t)(b * 8 + k) * 256 + hm];
  inv[b * 256 + hm] = 1.0f / s;
}

// ---------------------------------------------------------------------------
// GEMM B (round-9/10 structure, unchanged)
__global__ __launch_bounds__(512, 4) void gemm_b(const u16* __restrict__ lg,
                                                 const float* __restrict__ inv,
                                                 const u16* __restrict__ wvT,
                                                 const float* __restrict__ bvv,
                                                 float* __restrict__ out) {
  __shared__ u16 Ps[16384];
  const int t = threadIdx.x;
  const int l = t & 63, w = t >> 6;
  const int lrow = l & 15, lkg = l >> 4;
  const int gCol0 = blockIdx.x << 8;
  const int gRow0 = blockIdx.y << 6;
  const int bIdx = blockIdx.y >> 4;

  {
    const int r = t >> 3, ko = t & 7;
    const u16* src = lg + (size_t)(gRow0 + r) * 256 + ko * 32;
    const float* ivp = inv + bIdx * 256 + ko * 32;
    uint4 q[4];
    q[0] = ((const uint4*)src)[0];
    q[1] = ((const uint4*)src)[1];
    q[2] = ((const uint4*)src)[2];
    q[3] = ((const uint4*)src)[3];
    float4 iva[8];
#pragma unroll
    for (int c = 0; c < 8; c++) iva[c] = ((const float4*)ivp)[c];
    float e[32];
#pragma unroll
    for (int c = 0; c < 4; c++) {
      const u32 w0 = q[c].x, w1 = q[c].y, w2 = q[c].z, w3 = q[c].w;
      const float4 ia = iva[c * 2], ib = iva[c * 2 + 1];
      e[c * 8 + 0] = __expf(bf2f((u16)(w0 & 0xffffu))) * ia.x;
      e[c * 8 + 1] = __expf(bf2f((u16)(w0 >> 16)))     * ia.y;
      e[c * 8 + 2] = __expf(bf2f((u16)(w1 & 0xffffu))) * ia.z;
      e[c * 8 + 3] = __expf(bf2f((u16)(w1 >> 16)))     * ia.w;
      e[c * 8 + 4] = __expf(bf2f((u16)(w2 & 0xffffu))) * ib.x;
      e[c * 8 + 5] = __expf(bf2f((u16)(w2 >> 16)))     * ib.y;
      e[c * 8 + 6] = __expf(bf2f((u16)(w3 & 0xffffu))) * ib.z;
      e[c * 8 + 7] = __expf(bf2f((u16)(w3 >> 16)))     * ib.w;
    }
    float s0 = 0.f, s1 = 0.f;
#pragma unroll
    for (int p = 0; p < 16; p++) { s0 += e[p]; s1 += e[16 + p]; }
    const float r0 = 1.0f / (s0 + 1e-9f), r1 = 1.0f / (s1 + 1e-9f);
#pragma unroll
    for (int c = 0; c < 4; c++) {
      const float rs = (c < 2) ? r0 : r1;
      const uint4 cell = make_uint4(
          cvt2(e[c * 8 + 0] * rs, e[c * 8 + 1] * rs),
          cvt2(e[c * 8 + 2] * rs, e[c * 8 + 3] * rs),
          cvt2(e[c * 8 + 4] * rs, e[c * 8 + 5] * rs),
          cvt2(e[c * 8 + 6] * rs, e[c * 8 + 7] * rs));
      const int kg = ko * 4 + c;
      *(uint4*)&Ps[((r << 5) + (kg ^ (r & 7))) * 8] = cell;
    }
  }
  __syncthreads();

  f32x4 acc[4][2];
#pragma unroll
  for (int i = 0; i < 4; i++)
#pragma unroll
    for (int n = 0; n < 2; n++) acc[i][n] = f32x4{0.f, 0.f, 0.f, 0.f};

  const u16* bBase = wvT + (size_t)(gCol0 + w * 32 + lrow) * 256 + lkg * 8;
  uint4 bPre[2][2];
  bPre[0][0] = *(const uint4*)(bBase);
  bPre[0][1] = *(const uint4*)(bBase + 16 * 256);
  bPre[1][0] = *(const uint4*)(bBase + 32);
  bPre[1][1] = *(const uint4*)(bBase + 16 * 256 + 32);

#pragma unroll
  for (int kc = 0; kc < 8; ++kc) {
    const int d = kc & 1;
    s16x8 af[4];
#pragma unroll
    for (int i = 0; i < 4; i++)
      af[i] = *(const s16x8*)
          &Ps[(((i * 16 + lrow) << 5) + ((kc * 4 + lkg) ^ (lrow & 7))) * 8];
    const s16x8 b0 = as_s16x8(bPre[d][0]);
    const s16x8 b1 = as_s16x8(bPre[d][1]);
    if (kc + 2 < 8) {
      bPre[d][0] = *(const uint4*)(bBase + (kc + 2) * 32);
      bPre[d][1] = *(const uint4*)(bBase + 16 * 256 + (kc + 2) * 32);
    }
#pragma unroll
    for (int i = 0; i < 4; i++) {
      mfma_bf16(acc[i][0], af[i], b0);
      mfma_bf16(acc[i][1], af[i], b1);
    }
  }

  asm volatile("s_nop 7\n\ts_nop 7");
  const int crow = lkg * 4;
#pragma unroll
  for (int n = 0; n < 2; n++) {
    const int col = gCol0 + w * 32 + n * 16 + lrow;
    const float bias = bvv[col];
#pragma unroll
    for (int i = 0; i < 4; i++) {
      const int row0 = gRow0 + i * 16 + crow;
#pragma unroll
      for (int j = 0; j < 4; j++)
        out[(size_t)(row0 + j) * 512 + col] = acc[i][n][j] + bias;
    }
  }
}

// ---------------------------------------------------------------------------
// PROBE A: gemm_a body repeated R=4 into dead scratch.
// MODE 0: full (stage+compute+epi per rep)
// MODE 1: stage only on rep 0 (reps 1-3 = compute+epi on stale LDS)
// MODE 2: stage+compute per rep, NO epilogue (acc kept alive via asm)
template <int MODE>
__global__ __launch_bounds__(256, 4) void probe_a(const float* __restrict__ x,
                                                  const u16* __restrict__ wkT,
                                                  const float* __restrict__ bk,
                                                  u16* __restrict__ logits,
                                                  float* __restrict__ cpart) {
  __shared__ float Asf[4096];
  __shared__ u16 Bs[4096];
  __shared__ float cs[2][128];
  const int t = threadIdx.x;
  const int l = t & 63, w = t >> 6;
  const int wr = w >> 1, wc = w & 1;
  const int lrow = l & 15, lkg = l >> 4;
  const int gCol0 = blockIdx.x << 7;
  const int gRow0 = blockIdx.y << 7;

  const char* xb = (const char*)x;
  const char* wb = (const char*)wkT;
  const char* gA[4]; char* lA[4];
  const char* gB[2]; char* lB[2];
#pragma unroll
  for (int p = 0; p < 4; p++) {
    const int o = p * 4096 + t * 16;
    const int row = o >> 7, inner = o & 127;
    const int linner = inner ^ ((row & 7) << 4);
    gA[p] = xb + (size_t)(gRow0 + row) * 2048 + linner;
    lA[p] = (char*)Asf + o;
  }
#pragma unroll
  for (int p = 0; p < 2; p++) {
    const int c = p * 256 + t;
    const int kg = c >> 7, col = c & 127;
    gB[p] = wb + (size_t)(gCol0 + col) * 1024 + kg * 16;
    lB[p] = (char*)Bs + c * 16;
  }

  f32x4 acc[4][4];
  for (int rep = 0; rep < 4; ++rep) {
#pragma unroll
    for (int i = 0; i < 4; i++)
#pragma unroll
      for (int n = 0; n < 4; n++) acc[i][n] = f32x4{0.f, 0.f, 0.f, 0.f};

    for (int kc = 0; kc < 16; ++kc) {
      __syncthreads();
      if (MODE != 1 || rep == 0) {
#pragma unroll
        for (int p = 0; p < 4; p++) gl16(gA[p] + kc * 128, lA[p]);
#pragma unroll
        for (int p = 0; p < 2; p++) gl16(gB[p] + kc * 64, lB[p]);
      }
      __syncthreads();
      s16x8 af[4];
#pragma unroll
      for (int i = 0; i < 4; i++) {
        const int r = wr * 64 + i * 16 + lrow;
        const int iw0 = (lkg << 5) ^ ((r & 7) << 4);
        const float4 a0 = *(const float4*)&Asf[r * 32 + (iw0 >> 2)];
        const float4 a1 = *(const float4*)&Asf[r * 32 + ((iw0 ^ 16) >> 2)];
        af[i] = as_s16x8(pack_bf8(a0, a1));
      }
#pragma unroll
      for (int n = 0; n < 4; n++) {
        const s16x8 bfr =
            *(const s16x8*)&Bs[(lkg * 128 + wc * 64 + n * 16 + lrow) * 8];
#pragma unroll
        for (int i = 0; i < 4; i++) mfma_bf16(acc[i][n], af[i], bfr);
      }
    }

    if (MODE != 2) {
      asm volatile("s_nop 7\n\ts_nop 7");
      const int crow = lkg * 4;
      float esum[4];
#pragma unroll
      for (int n = 0; n < 4; n++) {
        const int col = gCol0 + wc * 64 + n * 16 + lrow;
        const float bias = bk[col];
        float es = 0.f;
#pragma unroll
        for (int i = 0; i < 4; i++) {
          const int row0 = gRow0 + wr * 64 + i * 16 + crow;
#pragma unroll
          for (int j = 0; j < 4; j++) {
            const u16 q = f2bf(acc[i][n][j] + bias);
            logits[(size_t)(row0 + j) * 256 + col] = q;
            es += __expf(bf2f(q));
          }
        }
        esum[n] = es;
      }
#pragma unroll
      for (int n = 0; n < 4; n++) {
        esum[n] += __shfl_xor(esum[n], 16);
        esum[n] += __shfl_xor(esum[n], 32);
      }
      if (l < 16) {
#pragma unroll
        for (int n = 0; n < 4; n++) cs[wr][wc * 64 + n * 16 + l] = esum[n];
      }
      __syncthreads();
      if (t < 128)
        cpart[(size_t)blockIdx.y * 256 + gCol0 + t] = cs[0][t] + cs[1][t];
    } else {
      // keep acc live without stores (rule: ablation-via-skip DCEs upstream)
      asm volatile("" :: "v"(acc[0][0]), "v"(acc[1][1]), "v"(acc[2][2]),
                         "v"(acc[3][3]));
    }
  }
}

// PROBE B: gemm_b body repeated R=4 into dead scratch.
__global__ __launch_bounds__(512, 4) void probe_b(const u16* __restrict__ lg,
                                                  const float* __restrict__ inv,
                                                  const u16* __restrict__ wvT,
                                                  const float* __restrict__ bvv,
                                                  float* __restrict__ out) {
  __shared__ u16 Ps[16384];
  const int t = threadIdx.x;
  const int l = t & 63, w = t >> 6;
  const int lrow = l & 15, lkg = l >> 4;
  const int gCol0 = blockIdx.x << 8;
  const int gRow0 = blockIdx.y << 6;
  const int bIdx = blockIdx.y >> 4;

  for (int rep = 0; rep < 4; ++rep) {
    __syncthreads();  // prior rep's Ps reads complete
    {
      const int r = t >> 3, ko = t & 7;
      const u16* src = lg + (size_t)(gRow0 + r) * 256 + ko * 32;
      const float* ivp = inv + bIdx * 256 + ko * 32;
      uint4 q[4];
      q[0] = ((const uint4*)src)[0];
      q[1] = ((const uint4*)src)[1];
      q[2] = ((const uint4*)src)[2];
      q[3] = ((const uint4*)src)[3];
      float4 iva[8];
#pragma unroll
      for (int c = 0; c < 8; c++) iva[c] = ((const float4*)ivp)[c];
      float e[32];
#pragma unroll
      for (int c = 0; c < 4; c++) {
        const u32 w0 = q[c].x, w1 = q[c].y, w2 = q[c].z, w3 = q[c].w;
        const float4 ia = iva[c * 2], ib = iva[c * 2 + 1];
        e[c * 8 + 0] = __expf(bf2f((u16)(w0 & 0xffffu))) * ia.x;
        e[c * 8 + 1] = __expf(bf2f((u16)(w0 >> 16)))     * ia.y;
        e[c * 8 + 2] = __expf(bf2f((u16)(w1 & 0xffffu))) * ia.z;
        e[c * 8 + 3] = __expf(bf2f((u16)(w1 >> 16)))     * ia.w;
        e[c * 8 + 4] = __expf(bf2f((u16)(w2 & 0xffffu))) * ib.x;
        e[c * 8 + 5] = __expf(bf2f((u16)(w2 >> 16)))     * ib.y;
        e[c * 8 + 6] = __expf(bf2f((u16)(w3 & 0xffffu))) * ib.z;
        e[c * 8 + 7] = __expf(bf2f((u16)(w3 >> 16)))     * ib.w;
      }
      float s0 = 0.f, s1 = 0.f;
#pragma unroll
      for (int p = 0; p < 16; p++) { s0 += e[p]; s1 += e[16 + p]; }
      const float r0 = 1.0f / (s0 + 1e-9f), r1 = 1.0f / (s1 + 1e-9f);
#pragma unroll
      for (int c = 0; c < 4; c++) {
        const float rs = (c < 2) ? r0 : r1;
        const uint4 cell = make_uint4(
            cvt2(e[c * 8 + 0] * rs, e[c * 8 + 1] * rs),
            cvt2(e[c * 8 + 2] * rs, e[c * 8 + 3] * rs),
            cvt2(e[c * 8 + 4] * rs, e[c * 8 + 5] * rs),
            cvt2(e[c * 8 + 6] * rs, e[c * 8 + 7] * rs));
        const int kg = ko * 4 + c;
        *(uint4*)&Ps[((r << 5) + (kg ^ (r & 7))) * 8] = cell;
      }
    }
    __syncthreads();

    f32x4 acc[4][2];
#pragma unroll
    for (int i = 0; i < 4; i++)
#pragma unroll
      for (int n = 0; n < 2; n++) acc[i][n] = f32x4{0.f, 0.f, 0.f, 0.f};

    const u16* bBase = wvT + (size_t)(gCol0 + w * 32 + lrow) * 256 + lkg * 8;
    uint4 bPre[2][2];
    bPre[0][0] = *(const uint4*)(bBase);
    bPre[0][1] = *(const uint4*)(bBase + 16 * 256);
    bPre[1][0] = *(const uint4*)(bBase + 32);
    bPre[1][1] = *(const uint4*)(bBase + 16 * 256 + 32);

#pragma unroll
    for (int kc = 0; kc < 8; ++kc) {
      const int d = kc & 1;
      s16x8 af[4];
#pragma unroll
      for (int i = 0; i < 4; i++)
        af[i] = *(const s16x8*)
            &Ps[(((i * 16 + lrow) << 5) + ((kc * 4 + lkg) ^ (lrow & 7))) * 8];
      const s16x8 b0 = as_s16x8(bPre[d][0]);
      const s16x8 b1 = as_s16x8(bPre[d][1]);
      if (kc + 2 < 8) {
        bPre[d][0] = *(const uint4*)(bBase + (kc + 2) * 32);
        bPre[d][1] = *(const uint4*)(bBase + 16 * 256 + (kc + 2) * 32);
      }
#pragma unroll
      for (int i = 0; i < 4; i++) {
        mfma_bf16(acc[i][0], af[i], b0);
        mfma_bf16(acc[i][1], af[i], b1);
      }
    }

    asm volatile("s_nop 7\n\ts_nop 7");
    const int crow = lkg * 4;
#pragma unroll
    for (int n = 0; n < 2; n++) {
      const int col = gCol0 + w * 32 + n * 16 + lrow;
      const float bias = bvv[col];
#pragma unroll
      for (int i = 0; i < 4; i++) {
        const int row0 = gRow0 + i * 16 + crow;
#pragma unroll
        for (int j = 0; j < 4; j++)
          out[(size_t)(row0 + j) * 512 + col] = acc[i][n][j] + bias;
      }
    }
  }
}

// ---------------------------------------------------------------------------
extern "C" void kernel_launch(void* const* d_in, const int* in_sizes, int n_in,
                              void* d_out, int out_size, void* d_ws, size_t ws_size,
                              hipStream_t stream) {
  (void)in_sizes; (void)n_in; (void)out_size; (void)ws_size;
  const float* x     = (const float*)d_in[0];
  const float* W_in  = (const float*)d_in[1];
  const float* b_in  = (const float*)d_in[2];
  const float* W_mk  = (const float*)d_in[3];
  const float* b_mk  = (const float*)d_in[4];
  const float* W_mv  = (const float*)d_in[5];
  const float* b_mv  = (const float*)d_in[6];
  const float* W_out = (const float*)d_in[7];
  const float* b_out = (const float*)d_in[8];

  char* ws = (char*)d_ws;
  u16*   wkT  = (u16*)(ws + OFF_WKT);
  u16*   wvT  = (u16*)(ws + OFF_WVT);
  float* bk   = (float*)(ws + OFF_BK);
  float* bv   = (float*)(ws + OFF_BV);
  float* inv  = (float*)(ws + OFF_INV);
  float* cp   = (float*)(ws + OFF_CP);
  u16*   lg   = (u16*)(ws + OFF_LOG);
  float* wvp  = (float*)(ws + OFF_WVP);
  float* bvp  = (float*)(ws + OFF_BVP);
  u16*   plg  = (u16*)(ws + OFF_PLOG);
  float* pcp  = (float*)(ws + OFF_PCP);
  float* pout = (float*)(ws + OFF_POUT);
  float* outp = (float*)d_out;

  // real pipeline (identical to round 10)
  prep_wkt<<<512, 256, 0, stream>>>(W_in, W_mk, wkT);
  wvt_part<<<128, 256, 0, stream>>>(W_mv, b_mv, W_out, wvp, bvp);
  wvt_fin<<<512, 256, 0, stream>>>(wvp, bvp, b_out, wvT, bv);
  prep_bk<<<1, 256, 0, stream>>>(b_in, W_mk, b_mk, bk);
  gemm_a<<<dim3(2, 256), 256, 0, stream>>>(x, wkT, bk, lg, cp);
  colsum_fin<<<32, 256, 0, stream>>>(cp, inv);
  gemm_b<<<dim3(2, 512), 512, 0, stream>>>(lg, inv, wvT, bv, outp);

  // diagnostic probes (outputs dead; removed next round)
  probe_a<0><<<dim3(2, 256), 256, 0, stream>>>(x, wkT, bk, plg, pcp);
  probe_a<1><<<dim3(2, 256), 256, 0, stream>>>(x, wkT, bk, plg, pcp);
  probe_a<2><<<dim3(2, 256), 256, 0, stream>>>(x, wkT, bk, plg, pcp);
  probe_b<<<dim3(2, 512), 512, 0, stream>>>(lg, inv, wvT, bv, pout);
}

// Round 12
// 75.506 us; speedup vs baseline: 6.2927x; 6.2927x over previous
//
#include <hip/hip_runtime.h>
#include <cstdint>
#include <cstddef>

// ---------------------------------------------------------------------------
// MultiHeadExternalAttention, algebraically collapsed:
//   logits = x @ Wk + bk ; attn = softmax_n -> L1_m ; out = attn @ Wv + bv
// B=32 N=1024 E=512 H=16 M=16 HM=256 ROWS=32768
// Round 12:
//  * wkT/wvT stored FRAG-CONTIGUOUS ([kg][col][8]) -> all B reads/stages are
//    lane-contiguous (16 cache lines/instr, was 64 = request-rate bound).
//  * gemm_a: 64x128 tile, grid(2,512)=4 blk/CU, dbuf global_load_lds with
//    stage(kc+1) issued BEFORE compute(kc), one syncthreads/step (T3/T4).
//  * gemm_b: conflict-free bijective Ps swizzle ((c<<3)|((ko+r)&7)),
//    af depth-1 LDS prefetch, contiguous wvT_f reads.
// ---------------------------------------------------------------------------

typedef unsigned short u16;
typedef unsigned int u32;
typedef short s16x8 __attribute__((ext_vector_type(8)));
typedef float f32x4 __attribute__((ext_vector_type(4)));

// workspace layout (bytes)
constexpr size_t OFF_WKT  = 1u << 20;                 // u16 [64][256][8] (256 KiB)
constexpr size_t OFF_WVT  = OFF_WKT + (1u << 18);     // u16 [32][512][8] (256 KiB)
constexpr size_t OFF_BK   = OFF_WVT + (1u << 18);     // f32 [256]
constexpr size_t OFF_BV   = OFF_BK + 4096;            // f32 [512]
constexpr size_t OFF_INV  = OFF_BV + 4096;            // f32 [32][256]
constexpr size_t OFF_CP   = 2u << 20;                 // f32 [512][256]
constexpr size_t OFF_LOG  = 4u << 20;                 // u16 [32768][256] (16 MiB)
constexpr size_t OFF_WVP  = 40u << 20;                // f32 partials (4 MiB)
constexpr size_t OFF_BVP  = 45u << 20;                // f32 partials (256 KiB)

__device__ __forceinline__ float bf2f(u16 v) {
  union { u32 u; float f; } c; c.u = ((u32)v) << 16; return c.f;
}
__device__ __forceinline__ u16 f2bf(float f) {
  union { float f; u32 u; } c; c.f = f;
  u32 u = c.u;
  u += 0x7fffu + ((u >> 16) & 1u);
  return (u16)(u >> 16);
}
__device__ __forceinline__ u32 cvt2(float lo, float hi) {
  u32 r;
  asm("v_cvt_pk_bf16_f32 %0, %1, %2" : "=v"(r) : "v"(lo), "v"(hi));
  return r;
}
__device__ __forceinline__ uint4 pack_bf8(float4 lo, float4 hi) {
  return make_uint4(cvt2(lo.x, lo.y), cvt2(lo.z, lo.w),
                    cvt2(hi.x, hi.y), cvt2(hi.z, hi.w));
}
__device__ __forceinline__ s16x8 as_s16x8(uint4 v) {
  union { uint4 u; s16x8 s; } c; c.u = v; return c.s;
}
__device__ __forceinline__ void mfma_bf16(f32x4& acc, s16x8 a, s16x8 b) {
  asm volatile("v_mfma_f32_16x16x32_bf16 %0, %1, %2, %0"
               : "+v"(acc) : "v"(a), "v"(b));
}
__device__ __forceinline__ void gl16(const void* g, void* l) {
  __builtin_amdgcn_global_load_lds(
      (const __attribute__((address_space(1))) void*)g,
      (__attribute__((address_space(3))) void*)l, 16, 0, 0);
}

// ---------------------------------------------------------------------------
// wkT_f[kg = e>>3][hm][idx = e&7] = sum_d W_in[e, h*128+d] * W_mk[d, m]
__global__ void prep_wkt(const float* __restrict__ wi, const float* __restrict__ wm,
                         u16* __restrict__ wkTf) {
  const int gid = blockIdx.x * 256 + threadIdx.x;
  const int hm = gid & 255, e = gid >> 8;
  const int h = hm >> 4, m = hm & 15;
  float acc = 0.f;
  for (int d = 0; d < 128; d++)
    acc += wi[e * 2048 + h * 128 + d] * wm[d * 16 + m];
  wkTf[((((size_t)(e >> 3)) * 256 + hm) << 3) + (e & 7)] = f2bf(acc);
}

// wvt partial: block = (h, dc); 16 d's per chunk; coalesced W_out rows.
__global__ __launch_bounds__(256) void wvt_part(const float* __restrict__ mv,
                                                const float* __restrict__ b_mv,
                                                const float* __restrict__ wo,
                                                float* __restrict__ wvp,
                                                float* __restrict__ bvp) {
  __shared__ float wmv_l[16][16];
  __shared__ float bmv_l[16];
  const int blk = blockIdx.x;
  const int h = blk >> 3, dc = blk & 7;
  const int t = threadIdx.x;
  {
    const int m = t >> 4, dd = t & 15;
    wmv_l[m][dd] = mv[m * 128 + dc * 16 + dd];
    if (t < 16) bmv_l[t] = b_mv[dc * 16 + t];
  }
  __syncthreads();
  float acc0[16], acc1[16];
  float bv0 = 0.f, bv1 = 0.f;
#pragma unroll
  for (int m = 0; m < 16; m++) { acc0[m] = 0.f; acc1[m] = 0.f; }
#pragma unroll
  for (int dd = 0; dd < 16; dd++) {
    const float w0 = wo[(size_t)(h * 128 + dc * 16 + dd) * 512 + t];
    const float w1 = wo[(size_t)(h * 128 + dc * 16 + dd) * 512 + 256 + t];
#pragma unroll
    for (int m = 0; m < 16; m++) {
      const float c = wmv_l[m][dd];
      acc0[m] += c * w0;
      acc1[m] += c * w1;
    }
    bv0 += bmv_l[dd] * w0;
    bv1 += bmv_l[dd] * w1;
  }
  float* w0p = wvp + ((size_t)blk * 512 + t) * 16;
  float* w1p = wvp + ((size_t)blk * 512 + 256 + t) * 16;
#pragma unroll
  for (int m = 0; m < 16; m++) { w0p[m] = acc0[m]; w1p[m] = acc1[m]; }
  bvp[(size_t)blk * 512 + t] = bv0;
  bvp[(size_t)blk * 512 + 256 + t] = bv1;
}

// wvT_f[kg = hm>>3][e][idx = hm&7] = f2bf(sum_dc wvp); bv = b_out + sum bvp
__global__ __launch_bounds__(256) void wvt_fin(const float* __restrict__ wvp,
                                               const float* __restrict__ bvp,
                                               const float* __restrict__ b_out,
                                               u16* __restrict__ wvTf,
                                               float* __restrict__ bv) {
  const int e = blockIdx.x;   // 512
  const int t = threadIdx.x;  // 256 = hm
  const int h = t >> 4, m = t & 15;
  float s = 0.f;
#pragma unroll
  for (int dc = 0; dc < 8; dc++)
    s += wvp[((size_t)(h * 8 + dc) * 512 + e) * 16 + m];
  wvTf[((((size_t)(t >> 3)) * 512 + e) << 3) + (t & 7)] = f2bf(s);
  if (t < 64) {
    float b = bvp[(size_t)t * 512 + e] + bvp[(size_t)(t + 64) * 512 + e];
#pragma unroll
    for (int mask = 32; mask >= 1; mask >>= 1) b += __shfl_xor(b, mask);
    if (t == 0) bv[e] = b_out[e] + b;
  }
}

// bk[hm] = b_mk[m] + sum_d b_in[h*128+d]*W_mk[d,m]
__global__ void prep_bk(const float* __restrict__ b_in, const float* __restrict__ wm,
                        const float* __restrict__ b_mk, float* __restrict__ bk) {
  const int t = threadIdx.x;
  const int h = t >> 4, m = t & 15;
  float acc = b_mk[m];
  for (int d = 0; d < 128; d++) acc += b_in[h * 128 + d] * wm[d * 16 + m];
  bk[t] = acc;
}

// ---------------------------------------------------------------------------
// GEMM A: logits[32768,256] = x @ Wk + bk (bf16) + colsum partials.
// Grid (2 colblk, 512 rowblk) = 1024 blocks (4/CU resident); 64x128 tile,
// BK=32, 256 thr (4 waves 2x2; wave = 32r x 64c, acc[2][4]).
// Double-buffered global_load_lds: stage(kc+1) issued BEFORE compute(kc);
// one __syncthreads (vmcnt0 drain) per step -> latency hidden by compute
// + 4-block co-residency.  A LDS: G4-XOR-swizzled fp32 via pre-swizzled
// source; B LDS: [kg][col] 16B cells from frag-contiguous wkT_f.
__global__ __launch_bounds__(256, 4) void gemm_a(const float* __restrict__ x,
                                                 const u16* __restrict__ wkTf,
                                                 const float* __restrict__ bk,
                                                 u16* __restrict__ logits,
                                                 float* __restrict__ cpart) {
  __shared__ float Asf[2][2048];  // 2 x 8 KB: 64 rows x 128 B (swizzled)
  __shared__ u16 Bs[2][4096];     // 2 x 8 KB: 4 kg x 128 col x 8 bf16
  __shared__ float cs[2][128];
  const int t = threadIdx.x;
  const int l = t & 63, w = t >> 6;
  const int wr = w >> 1, wc = w & 1;
  const int lrow = l & 15, lkg = l >> 4;
  const int gCol0 = blockIdx.x << 7;
  const int gRow0 = blockIdx.y << 6;

  // per-thread staging addresses (A source pre-swizzled; LDS dests linear,
  // wave-contiguous lane x 16 B as global_load_lds requires)
  const char* xb = (const char*)x;
  const char* wb = (const char*)wkTf;
  const char* gA[2]; int lAo[2];
  const char* gB[2]; int lBo[2];
#pragma unroll
  for (int p = 0; p < 2; p++) {
    const int o = p * 4096 + t * 16;              // A byte 0..8191
    const int row = o >> 7, inner = o & 127;
    const int linner = inner ^ ((row & 7) << 4);  // logical byte in row
    gA[p] = xb + (size_t)(gRow0 + row) * 2048 + linner;
    lAo[p] = o;
    const int c = p * 256 + t;                    // B cell 0..511
    const int kgl = c >> 7, col = c & 127;
    gB[p] = wb + ((size_t)kgl * 256 + gCol0 + col) * 16;
    lBo[p] = c * 16;
  }

  f32x4 acc[2][4];
#pragma unroll
  for (int i = 0; i < 2; i++)
#pragma unroll
    for (int n = 0; n < 4; n++) acc[i][n] = f32x4{0.f, 0.f, 0.f, 0.f};

  // prologue: stage kc=0 into buf 0
#pragma unroll
  for (int p = 0; p < 2; p++) {
    gl16(gA[p], (char*)Asf + lAo[p]);
    gl16(gB[p], (char*)Bs + lBo[p]);
  }
  __syncthreads();

  for (int kc = 0; kc < 16; ++kc) {
    const int buf = kc & 1;
    if (kc < 15) {
      const int nb = buf ^ 1;
#pragma unroll
      for (int p = 0; p < 2; p++) {
        gl16(gA[p] + (size_t)(kc + 1) * 128, (char*)Asf + nb * 8192 + lAo[p]);
        gl16(gB[p] + (size_t)(kc + 1) * 16384, (char*)Bs + nb * 8192 + lBo[p]);
      }
    }
    s16x8 af[2];
#pragma unroll
    for (int i = 0; i < 2; i++) {
      const int r = wr * 32 + i * 16 + lrow;
      const int iw0 = (lkg << 5) ^ ((r & 7) << 4);
      const float4 a0 = *(const float4*)&Asf[buf][r * 32 + (iw0 >> 2)];
      const float4 a1 = *(const float4*)&Asf[buf][r * 32 + ((iw0 ^ 16) >> 2)];
      af[i] = as_s16x8(pack_bf8(a0, a1));
    }
#pragma unroll
    for (int n = 0; n < 4; n++) {
      const s16x8 bfr =
          *(const s16x8*)&Bs[buf][(lkg * 128 + wc * 64 + n * 16 + lrow) * 8];
#pragma unroll
      for (int i = 0; i < 2; i++) mfma_bf16(acc[i][n], af[i], bfr);
    }
    __syncthreads();  // vmcnt(0): next-tile staged; all reads of buf done
  }

  asm volatile("s_nop 7\n\ts_nop 7");
  const int crow = lkg * 4;  // C/D: row = (l>>4)*4 + j, col = l&15
  float esum[4];
#pragma unroll
  for (int n = 0; n < 4; n++) {
    const int col = gCol0 + wc * 64 + n * 16 + lrow;
    const float bias = bk[col];
    float es = 0.f;
#pragma unroll
    for (int i = 0; i < 2; i++) {
      const int row0 = gRow0 + wr * 32 + i * 16 + crow;
#pragma unroll
      for (int j = 0; j < 4; j++) {
        const u16 q = f2bf(acc[i][n][j] + bias);
        logits[(size_t)(row0 + j) * 256 + col] = q;
        es += __expf(bf2f(q));
      }
    }
    esum[n] = es;
  }
#pragma unroll
  for (int n = 0; n < 4; n++) {
    esum[n] += __shfl_xor(esum[n], 16);
    esum[n] += __shfl_xor(esum[n], 32);
  }
  if (l < 16) {
#pragma unroll
    for (int n = 0; n < 4; n++) cs[wr][wc * 64 + n * 16 + l] = esum[n];
  }
  __syncthreads();
  if (t < 128)
    cpart[(size_t)blockIdx.y * 256 + gCol0 + t] = cs[0][t] + cs[1][t];
}

// inv[b][hm] = 1 / sum over the batch's 16 row-block partials
__global__ void colsum_fin(const float* __restrict__ cpart, float* __restrict__ inv) {
  const int b = blockIdx.x, hm = threadIdx.x;
  float s = 0.f;
#pragma unroll
  for (int k = 0; k < 16; k++) s += cpart[(size_t)(b * 16 + k) * 256 + hm];
  inv[b * 256 + hm] = 1.0f / s;
}

// ---------------------------------------------------------------------------
// GEMM B: out[32768,512] = P @ Wv + bv (fp32 out).
// Grid (2 colblk, 512 rowblk); block = 64 rows x 256 cols, 8 waves
// (wave = 64r x 32c, acc[4][2]).
// Phase 1: P[64][256] -> 32 KiB LDS with BIJECTIVE conflict-free swizzle:
//   logical cell kg = ko*4+c at row r -> phys = (c<<3) | ((ko + r) & 7)
//   (writer octets: ko 0..7 -> 8 distinct granules; reader octets: lrow
//    0..7 -> 8 distinct granules; bijective per row).
// Phase 2: MFMA loop, af depth-1 LDS prefetch, B from frag-contiguous wvT_f
// (lane-contiguous reads), depth-2 global prefetch. No K-loop barriers.
__global__ __launch_bounds__(512, 4) void gemm_b(const u16* __restrict__ lg,
                                                 const float* __restrict__ inv,
                                                 const u16* __restrict__ wvTf,
                                                 const float* __restrict__ bvv,
                                                 float* __restrict__ out) {
  __shared__ u16 Ps[16384];  // 64 rows x 32 cells x 8 bf16 = 32 KiB
  const int t = threadIdx.x;
  const int l = t & 63, w = t >> 6;
  const int lrow = l & 15, lkg = l >> 4;
  const int gCol0 = blockIdx.x << 8;
  const int gRow0 = blockIdx.y << 6;
  const int bIdx = blockIdx.y >> 4;

  // ---- phase 1 (contiguous reads: thread t covers bytes t*64..t*64+63) ----
  {
    const int r = t >> 3, ko = t & 7;
    const u16* src = lg + (size_t)(gRow0 + r) * 256 + ko * 32;
    const float* ivp = inv + bIdx * 256 + ko * 32;
    uint4 q[4];
    q[0] = ((const uint4*)src)[0];
    q[1] = ((const uint4*)src)[1];
    q[2] = ((const uint4*)src)[2];
    q[3] = ((const uint4*)src)[3];
    float4 iva[8];
#pragma unroll
    for (int c = 0; c < 8; c++) iva[c] = ((const float4*)ivp)[c];
    float e[32];
#pragma unroll
    for (int c = 0; c < 4; c++) {
      const u32 w0 = q[c].x, w1 = q[c].y, w2 = q[c].z, w3 = q[c].w;
      const float4 ia = iva[c * 2], ib = iva[c * 2 + 1];
      e[c * 8 + 0] = __expf(bf2f((u16)(w0 & 0xffffu))) * ia.x;
      e[c * 8 + 1] = __expf(bf2f((u16)(w0 >> 16)))     * ia.y;
      e[c * 8 + 2] = __expf(bf2f((u16)(w1 & 0xffffu))) * ia.z;
      e[c * 8 + 3] = __expf(bf2f((u16)(w1 >> 16)))     * ia.w;
      e[c * 8 + 4] = __expf(bf2f((u16)(w2 & 0xffffu))) * ib.x;
      e[c * 8 + 5] = __expf(bf2f((u16)(w2 >> 16)))     * ib.y;
      e[c * 8 + 6] = __expf(bf2f((u16)(w3 & 0xffffu))) * ib.z;
      e[c * 8 + 7] = __expf(bf2f((u16)(w3 >> 16)))     * ib.w;
    }
    float s0 = 0.f, s1 = 0.f;
#pragma unroll
    for (int p = 0; p < 16; p++) { s0 += e[p]; s1 += e[16 + p]; }
    const float r0 = 1.0f / (s0 + 1e-9f), r1 = 1.0f / (s1 + 1e-9f);
#pragma unroll
    for (int c = 0; c < 4; c++) {
      const float rs = (c < 2) ? r0 : r1;
      const uint4 cell = make_uint4(
          cvt2(e[c * 8 + 0] * rs, e[c * 8 + 1] * rs),
          cvt2(e[c * 8 + 2] * rs, e[c * 8 + 3] * rs),
          cvt2(e[c * 8 + 4] * rs, e[c * 8 + 5] * rs),
          cvt2(e[c * 8 + 6] * rs, e[c * 8 + 7] * rs));
      const int phys = (c << 3) | ((ko + r) & 7);
      *(uint4*)&Ps[((r << 5) + phys) * 8] = cell;
    }
  }
  __syncthreads();

  // ---- phase 2 ----
  f32x4 acc[4][2];
#pragma unroll
  for (int i = 0; i < 4; i++)
#pragma unroll
    for (int n = 0; n < 2; n++) acc[i][n] = f32x4{0.f, 0.f, 0.f, 0.f};

  // frag-contiguous B: addr = ((kc*4+lkg)*512 + col)*8 u16
  const u16* bBase = wvTf + ((size_t)lkg * 512 + gCol0 + w * 32 + lrow) * 8;
  uint4 bPre[2][2];
#pragma unroll
  for (int n = 0; n < 2; n++) {
    bPre[0][n] = *(const uint4*)(bBase + n * 128);
    bPre[1][n] = *(const uint4*)(bBase + 16384 + n * 128);
  }
  s16x8 af[2][4];
#pragma unroll
  for (int i = 0; i < 4; i++) {
    const int r = i * 16 + lrow;
    const int phys = (lkg << 3) | ((0 + r) & 7);
    af[0][i] = *(const s16x8*)&Ps[((r << 5) + phys) * 8];
  }

#pragma unroll
  for (int kc = 0; kc < 8; ++kc) {
    const int d = kc & 1;
    if (kc < 7) {
#pragma unroll
      for (int i = 0; i < 4; i++) {
        const int r = i * 16 + lrow;
        const int phys = (lkg << 3) | ((kc + 1 + r) & 7);
        af[d ^ 1][i] = *(const s16x8*)&Ps[((r << 5) + phys) * 8];
      }
    }
    const s16x8 b0 = as_s16x8(bPre[d][0]);
    const s16x8 b1 = as_s16x8(bPre[d][1]);
    if (kc + 2 < 8) {
#pragma unroll
      for (int n = 0; n < 2; n++)
        bPre[d][n] = *(const uint4*)(bBase + (size_t)(kc + 2) * 16384 + n * 128);
    }
#pragma unroll
    for (int i = 0; i < 4; i++) {
      mfma_bf16(acc[i][0], af[d][i], b0);
      mfma_bf16(acc[i][1], af[d][i], b1);
    }
  }

  asm volatile("s_nop 7\n\ts_nop 7");
  const int crow = lkg * 4;
#pragma unroll
  for (int n = 0; n < 2; n++) {
    const int col = gCol0 + w * 32 + n * 16 + lrow;
    const float bias = bvv[col];
#pragma unroll
    for (int i = 0; i < 4; i++) {
      const int row0 = gRow0 + i * 16 + crow;
#pragma unroll
      for (int j = 0; j < 4; j++)
        out[(size_t)(row0 + j) * 512 + col] = acc[i][n][j] + bias;
    }
  }
}

// ---------------------------------------------------------------------------
extern "C" void kernel_launch(void* const* d_in, const int* in_sizes, int n_in,
                              void* d_out, int out_size, void* d_ws, size_t ws_size,
                              hipStream_t stream) {
  (void)in_sizes; (void)n_in; (void)out_size; (void)ws_size;
  const float* x     = (const float*)d_in[0];
  const float* W_in  = (const float*)d_in[1];
  const float* b_in  = (const float*)d_in[2];
  const float* W_mk  = (const float*)d_in[3];
  const float* b_mk  = (const float*)d_in[4];
  const float* W_mv  = (const float*)d_in[5];
  const float* b_mv  = (const float*)d_in[6];
  const float* W_out = (const float*)d_in[7];
  const float* b_out = (const float*)d_in[8];

  char* ws = (char*)d_ws;
  u16*   wkTf = (u16*)(ws + OFF_WKT);
  u16*   wvTf = (u16*)(ws + OFF_WVT);
  float* bk   = (float*)(ws + OFF_BK);
  float* bv   = (float*)(ws + OFF_BV);
  float* inv  = (float*)(ws + OFF_INV);
  float* cp   = (float*)(ws + OFF_CP);
  u16*   lg   = (u16*)(ws + OFF_LOG);
  float* wvp  = (float*)(ws + OFF_WVP);
  float* bvp  = (float*)(ws + OFF_BVP);
  float* outp = (float*)d_out;

  prep_wkt<<<512, 256, 0, stream>>>(W_in, W_mk, wkTf);
  wvt_part<<<128, 256, 0, stream>>>(W_mv, b_mv, W_out, wvp, bvp);
  wvt_fin<<<512, 256, 0, stream>>>(wvp, bvp, b_out, wvTf, bv);
  prep_bk<<<1, 256, 0, stream>>>(b_in, W_mk, b_mk, bk);
  gemm_a<<<dim3(2, 512), 256, 0, stream>>>(x, wkTf, bk, lg, cp);
  colsum_fin<<<32, 256, 0, stream>>>(cp, inv);
  gemm_b<<<dim3(2, 512), 512, 0, stream>>>(lg, inv, wvTf, bv, outp);
}